// Round 1
// baseline (6399.697 us; speedup 1.0000x reference)
//
#include <hip/hip_runtime.h>
#include <math.h>

#define N_NODES 50000
#define N_EDGES 800000
#define N_GRAPHS 100
#define IN_DIM 100
#define D 128
#define N_ETYPES 4
#define N_STEPS 8

// h[n][d] = d < IN_DIM ? features[n][d] : 0
__global__ void pad_kernel(const float* __restrict__ feat, float* __restrict__ h) {
    int idx = blockIdx.x * blockDim.x + threadIdx.x;
    if (idx >= N_NODES * D) return;
    int n = idx >> 7, d = idx & 127;
    h[idx] = (d < IN_DIM) ? feat[n * IN_DIM + d] : 0.0f;
}

// Build fused GRU weight matrix Wg[256][512]:
//   cols [0,256):  p = gi + gh for r,z gates   (K: 0..127 from a via W_ih, 128..255 from h via W_hh)
//   cols [256,384): i_n  (from a only, W_ih rows 256..383)
//   cols [384,512): h_n  (from h only, W_hh rows 256..383)
__global__ void build_wg(const float* __restrict__ W_ih, const float* __restrict__ W_hh,
                         float* __restrict__ Wg) {
    int idx = blockIdx.x * blockDim.x + threadIdx.x;
    if (idx >= 256 * 512) return;
    int k = idx >> 9, j = idx & 511;
    float v;
    if (j < 256)      v = (k < 128) ? W_ih[j * 128 + k] : W_hh[j * 128 + (k - 128)];
    else if (j < 384) v = (k < 128) ? W_ih[j * 128 + k] : 0.0f;
    else              v = (k < 128) ? 0.0f : W_hh[(j - 128) * 128 + (k - 128)];
    Wg[idx] = v;
}

// C[M][N] = concat(A0[M][K0] | A1[M][K-K0]) @ B[K][N], all row-major fp32.
// 64x64 tile, 256 threads (16x16), 4x4 micro-tile, K-chunk 16. Requires N%64==0, K%16==0, K0%16==0.
__global__ __launch_bounds__(256) void gemm_kernel(
    const float* __restrict__ A0, const float* __restrict__ A1,
    const float* __restrict__ B, float* __restrict__ C,
    int M, int K0, int K, int N) {
  __shared__ float As[16][64];
  __shared__ float Bs[16][64];
  int tid = threadIdx.x;
  int tx = tid & 15, ty = tid >> 4;
  int m0 = blockIdx.x * 64, n0 = blockIdx.y * 64;
  int K1 = K - K0;
  float c[4][4] = {{0.f}};
  for (int k0 = 0; k0 < K; k0 += 16) {
    // A tile: 64 rows x 16 k, float4 per thread
    {
      int q = tid * 4;
      int m_l = q >> 4;
      int k_l = q & 15;
      int m = m0 + m_l;
      float4 v = make_float4(0.f, 0.f, 0.f, 0.f);
      if (m < M) {
        int kg = k0 + k_l;
        const float* src = (kg < K0) ? (A0 + (size_t)m * K0 + kg)
                                     : (A1 + (size_t)m * K1 + (kg - K0));
        v = *(const float4*)src;
      }
      As[k_l + 0][m_l] = v.x;
      As[k_l + 1][m_l] = v.y;
      As[k_l + 2][m_l] = v.z;
      As[k_l + 3][m_l] = v.w;
    }
    // B tile: 16 k x 64 cols, float4 per thread
    {
      int q = tid * 4;
      int k_l = q >> 6;
      int n_l = q & 63;
      float4 v = *(const float4*)(B + (size_t)(k0 + k_l) * N + n0 + n_l);
      *(float4*)&Bs[k_l][n_l] = v;
    }
    __syncthreads();
    #pragma unroll
    for (int kk = 0; kk < 16; ++kk) {
      float4 av = *(const float4*)&As[kk][ty * 4];
      float4 bv = *(const float4*)&Bs[kk][tx * 4];
      c[0][0] += av.x * bv.x; c[0][1] += av.x * bv.y; c[0][2] += av.x * bv.z; c[0][3] += av.x * bv.w;
      c[1][0] += av.y * bv.x; c[1][1] += av.y * bv.y; c[1][2] += av.y * bv.z; c[1][3] += av.y * bv.w;
      c[2][0] += av.z * bv.x; c[2][1] += av.z * bv.y; c[2][2] += av.z * bv.z; c[2][3] += av.z * bv.w;
      c[3][0] += av.w * bv.x; c[3][1] += av.w * bv.y; c[3][2] += av.w * bv.z; c[3][3] += av.w * bv.w;
    }
    __syncthreads();
  }
  #pragma unroll
  for (int i = 0; i < 4; ++i) {
    int m = m0 + ty * 4 + i;
    if (m < M) {
      float4 v = make_float4(c[i][0], c[i][1], c[i][2], c[i][3]);
      *(float4*)(C + (size_t)m * N + n0 + tx * 4) = v;
    }
  }
}

// One 32-lane group per edge; pass handles only edges of type t.
// a[dst][:] += T[src][:] + b_msg[t][:]
__global__ __launch_bounds__(256) void scatter_kernel(
    const int* __restrict__ esrc, const int* __restrict__ edst, const int* __restrict__ etype,
    const float* __restrict__ T, const float* __restrict__ bmsg_t, int t,
    float* __restrict__ a) {
  int gid = blockIdx.x * 256 + threadIdx.x;
  int e = gid >> 5;
  int lane = gid & 31;
  if (e >= N_EDGES) return;
  if (etype[e] != t) return;
  int s = esrc[e], dd = edst[e];
  const float* trow = T + (size_t)s * D;
  float* arow = a + (size_t)dd * D;
  #pragma unroll
  for (int i = 0; i < 4; ++i) {
    int d = lane + i * 32;
    atomicAdd(&arow[d], trow[d] + bmsg_t[d]);
  }
}

// Elementwise GRU gate math; h updated in place.
__global__ void gru_kernel(const float* __restrict__ G, const float* __restrict__ b_ih,
                           const float* __restrict__ b_hh, float* __restrict__ h) {
  int idx = blockIdx.x * blockDim.x + threadIdx.x;
  if (idx >= N_NODES * D) return;
  int n = idx >> 7, d = idx & 127;
  const float* g = G + (size_t)n * 512;
  float pr  = g[d]       + b_ih[d]       + b_hh[d];
  float pz  = g[128 + d] + b_ih[128 + d] + b_hh[128 + d];
  float in_ = g[256 + d] + b_ih[256 + d];
  float hn  = g[384 + d] + b_hh[256 + d];
  float r = 1.0f / (1.0f + expf(-pr));
  float z = 1.0f / (1.0f + expf(-pz));
  float nn = tanhf(in_ + r * hn);
  float hv = h[idx];
  h[idx] = (1.0f - z) * nn + z * hv;
}

__global__ void pool_kernel(const float* __restrict__ h, const int* __restrict__ gids,
                            float* __restrict__ pooled, float* __restrict__ gcnt) {
  int idx = blockIdx.x * blockDim.x + threadIdx.x;
  if (idx >= N_NODES * D) return;
  int n = idx >> 7, d = idx & 127;
  int g = gids[n];
  atomicAdd(&pooled[g * D + d], h[idx]);
  if (d == 0) atomicAdd(&gcnt[g], 1.0f);
}

__global__ __launch_bounds__(256) void classifier_kernel(
    const float* __restrict__ pooled, const float* __restrict__ gcnt,
    const float* __restrict__ W1, const float* __restrict__ b1,
    const float* __restrict__ W2, const float* __restrict__ b2,
    float* __restrict__ out) {
  __shared__ float p[D];
  __shared__ float hid[256];
  __shared__ float wsum[4];
  int g = blockIdx.x;
  int t = threadIdx.x;
  float cnt = fmaxf(gcnt[g], 1.0f);
  if (t < D) p[t] = pooled[g * D + t] / cnt;
  __syncthreads();
  float acc = b1[t];
  const float* w = W1 + (size_t)t * D;
  for (int k = 0; k < D; ++k) acc += p[k] * w[k];
  hid[t] = fmaxf(acc, 0.0f);
  __syncthreads();
  float v = hid[t] * W2[t];
  for (int off = 32; off > 0; off >>= 1) v += __shfl_down(v, off, 64);
  if ((t & 63) == 0) wsum[t >> 6] = v;
  __syncthreads();
  if (t == 0) {
    float s = wsum[0] + wsum[1] + wsum[2] + wsum[3] + b2[0];
    out[g] = 1.0f / (1.0f + expf(-s));
  }
}

extern "C" void kernel_launch(void* const* d_in, const int* in_sizes, int n_in,
                              void* d_out, int out_size, void* d_ws, size_t ws_size,
                              hipStream_t stream) {
  const float* features = (const float*)d_in[0];
  const int* esrc  = (const int*)d_in[1];
  const int* edst  = (const int*)d_in[2];
  const int* etype = (const int*)d_in[3];
  const int* gids  = (const int*)d_in[4];
  const float* W_msg = (const float*)d_in[5];
  const float* b_msg = (const float*)d_in[6];
  const float* W_ih  = (const float*)d_in[7];
  const float* W_hh  = (const float*)d_in[8];
  const float* b_ih  = (const float*)d_in[9];
  const float* b_hh  = (const float*)d_in[10];
  const float* W1 = (const float*)d_in[11];
  const float* b1 = (const float*)d_in[12];
  const float* W2 = (const float*)d_in[13];
  const float* b2 = (const float*)d_in[14];
  float* out = (float*)d_out;

  char* ws = (char*)d_ws;
  size_t off = 0;
  auto alloc = [&](size_t bytes) -> void* {
    void* p = ws + off;
    off += (bytes + 255) & ~(size_t)255;
    return p;
  };
  float* h   = (float*)alloc((size_t)N_NODES * D * 4);      // 25.6 MB
  float* a   = (float*)alloc((size_t)N_NODES * D * 4);      // 25.6 MB
  float* G   = (float*)alloc((size_t)N_NODES * 512 * 4);    // 102.4 MB
  float* T   = G;  // T's lifetime (gemm->scatter) ends before G is written
  float* Wg  = (float*)alloc(256 * 512 * 4);
  float* pooled = (float*)alloc(N_GRAPHS * D * 4);
  float* gcnt   = (float*)alloc(N_GRAPHS * 4);

  pad_kernel<<<(N_NODES * D + 255) / 256, 256, 0, stream>>>(features, h);
  build_wg<<<(256 * 512 + 255) / 256, 256, 0, stream>>>(W_ih, W_hh, Wg);

  for (int step = 0; step < N_STEPS; ++step) {
    hipMemsetAsync(a, 0, (size_t)N_NODES * D * 4, stream);
    for (int t = 0; t < N_ETYPES; ++t) {
      gemm_kernel<<<dim3((N_NODES + 63) / 64, D / 64), 256, 0, stream>>>(
          h, h, W_msg + (size_t)t * D * D, T, N_NODES, D, D, D);
      scatter_kernel<<<(N_EDGES * 32) / 256, 256, 0, stream>>>(
          esrc, edst, etype, T, b_msg + (size_t)t * D, t, a);
    }
    gemm_kernel<<<dim3((N_NODES + 63) / 64, 512 / 64), 256, 0, stream>>>(
        a, h, Wg, G, N_NODES, D, 256, 512);
    gru_kernel<<<(N_NODES * D + 255) / 256, 256, 0, stream>>>(G, b_ih, b_hh, h);
  }

  hipMemsetAsync(pooled, 0, (size_t)N_GRAPHS * D * 4, stream);
  hipMemsetAsync(gcnt, 0, (size_t)N_GRAPHS * 4, stream);
  pool_kernel<<<(N_NODES * D + 255) / 256, 256, 0, stream>>>(h, gids, pooled, gcnt);
  classifier_kernel<<<N_GRAPHS, 256, 0, stream>>>(pooled, gcnt, W1, b1, W2, b2, out);
}

// Round 2
// 1786.333 us; speedup vs baseline: 3.5826x; 3.5826x over previous
//
#include <hip/hip_runtime.h>
#include <hip/hip_bf16.h>
#include <math.h>

#define N_NODES 50000
#define M_PAD   50048   // 391 * 128
#define N_EDGES 800000
#define N_GRAPHS 100
#define IN_DIM 100
#define D 128
#define N_STEPS 8

typedef unsigned short ushort_t;
typedef __bf16 bf16x8 __attribute__((ext_vector_type(8)));
typedef float f32x4 __attribute__((ext_vector_type(4)));

__device__ inline ushort_t f2b(float f) {
  __hip_bfloat16 b = __float2bfloat16(f);
  return *reinterpret_cast<ushort_t*>(&b);
}

// h[n][d] = d < IN_DIM ? features[n][d] : 0   (fp32 master state)
__global__ void pad_kernel(const float* __restrict__ feat, float* __restrict__ h) {
  int idx = blockIdx.x * blockDim.x + threadIdx.x;
  if (idx >= N_NODES * D) return;
  int n = idx >> 7, d = idx & 127;
  h[idx] = (d < IN_DIM) ? feat[n * IN_DIM + d] : 0.0f;
}

// ah[n][128+d] = bf16(h[n][d])
__global__ void cast_h_kernel(const float* __restrict__ h, ushort_t* __restrict__ ah) {
  int idx = blockIdx.x * blockDim.x + threadIdx.x;
  if (idx >= N_NODES * D) return;
  int n = idx >> 7, d = idx & 127;
  ah[(size_t)n * 256 + 128 + d] = f2b(h[idx]);
}

// WmsgT[col][k] = bf16(W_msg[t][k][f]), col = t*128+f  (n-major, k-contiguous)
__global__ void prep_wmsg(const float* __restrict__ W_msg, ushort_t* __restrict__ WmsgT) {
  int idx = blockIdx.x * blockDim.x + threadIdx.x;
  if (idx >= 512 * 128) return;
  int col = idx >> 7, k = idx & 127;
  int t = col >> 7, f = col & 127;
  WmsgT[col * 128 + k] = f2b(W_msg[((size_t)t * 128 + k) * 128 + f]);
}

// Permuted fused GRU weight, n-major k-contiguous bf16.
// col' = g*64 + gate*16 + r ; dim d = g*16 + r ; K: k<128 = a (W_ih), k>=128 = h (W_hh)
// gate 0: r-gate (j0=d), 1: z (j0=128+d), 2: i_n (j0=256+d, a only), 3: h_n (j0=384+d, h only)
__global__ void prep_wg(const float* __restrict__ W_ih, const float* __restrict__ W_hh,
                        const float* __restrict__ b_ih, const float* __restrict__ b_hh,
                        ushort_t* __restrict__ WgT, float* __restrict__ gbias) {
  int idx = blockIdx.x * blockDim.x + threadIdx.x;
  if (idx >= 512 * 256) return;
  int colp = idx >> 8, k = idx & 255;
  int g = colp >> 6, gate = (colp >> 4) & 3, r = colp & 15;
  int d = g * 16 + r;
  float v;
  if (gate == 3)      v = (k < 128) ? 0.f : W_hh[(size_t)(256 + d) * 128 + (k - 128)];
  else if (gate == 2) v = (k < 128) ? W_ih[(size_t)(256 + d) * 128 + k] : 0.f;
  else {
    int j0 = (gate == 0) ? d : 128 + d;
    v = (k < 128) ? W_ih[(size_t)j0 * 128 + k] : W_hh[(size_t)j0 * 128 + (k - 128)];
  }
  WgT[(size_t)colp * 256 + k] = f2b(v);
  if (k == 0) {
    float bb = (gate == 0) ? b_ih[d] + b_hh[d]
             : (gate == 1) ? b_ih[128 + d] + b_hh[128 + d]
             : (gate == 2) ? b_ih[256 + d] : b_hh[256 + d];
    gbias[colp] = bb;
  }
}

// ---- CSR build (edges static per launch) ----
__global__ void hist_kernel(const int* __restrict__ edst, int* __restrict__ cnt) {
  int e = blockIdx.x * 256 + threadIdx.x;
  if (e >= N_EDGES) return;
  atomicAdd(&cnt[edst[e]], 1);
}

__global__ __launch_bounds__(1024) void scan_kernel(const int* __restrict__ cnt,
                                                    int* __restrict__ off) {
  __shared__ int buf[1024];
  __shared__ int carry_s;
  int t = threadIdx.x;
  if (t == 0) { carry_s = 0; off[0] = 0; }
  __syncthreads();
  for (int base = 0; base < N_NODES; base += 1024) {
    int i = base + t;
    int v = (i < N_NODES) ? cnt[i] : 0;
    buf[t] = v;
    __syncthreads();
    for (int s = 1; s < 1024; s <<= 1) {
      int add = (t >= s) ? buf[t - s] : 0;
      __syncthreads();
      buf[t] += add;
      __syncthreads();
    }
    int carry = carry_s;
    if (i < N_NODES) off[i + 1] = carry + buf[t];
    __syncthreads();
    if (t == 1023) carry_s = carry + buf[1023];
    __syncthreads();
  }
}

__global__ void fill_kernel(const int* __restrict__ esrc, const int* __restrict__ edst,
                            const int* __restrict__ etype, const int* __restrict__ off,
                            int* __restrict__ cursor, int* __restrict__ payload) {
  int e = blockIdx.x * 256 + threadIdx.x;
  if (e >= N_EDGES) return;
  int dd = edst[e];
  int pos = atomicAdd(&cursor[dd], 1);
  payload[off[dd] + pos] = (esrc[e] << 2) | etype[e];
}

// a[n][d] = sum over incoming edges of T[src][t*128+d]; write bf16 into ah a-part.
// (b_msg already folded into T by the GEMM epilogue.)
__global__ __launch_bounds__(128) void gather_kernel(const int* __restrict__ off,
    const int* __restrict__ payload, const float* __restrict__ T,
    ushort_t* __restrict__ ah) {
  int n = blockIdx.x;
  int d = threadIdx.x;
  int s = off[n], e = off[n + 1];
  float acc = 0.f;
  for (int i = s; i < e; ++i) {
    int p = payload[i];
    acc += T[(size_t)(p >> 2) * 512 + (p & 3) * 128 + d];
  }
  ah[(size_t)n * 256 + d] = f2b(acc);
}

// ---- bf16 MFMA GEMM, 128x128 tile, 4 waves, 16x16x32 ----
// A [M_PAD][lda] bf16 row-major (ptr may be pre-offset), Bt [512][K] bf16 n-major.
// MODE 0: C[m][n] = acc + bias[n]  (T output, ldc=512)
// MODE 1: GRU epilogue on permuted gate columns; updates h fp32 in place.
template <int MODE>
__global__ __launch_bounds__(256) void mfma_gemm(
    const ushort_t* __restrict__ A, int lda, int K,
    const ushort_t* __restrict__ Bt,
    float* __restrict__ C, const float* __restrict__ bias,
    float* __restrict__ h) {
  __shared__ ushort_t As[128][40];   // stride 40 bf16 = 80 B: 16B-aligned, 2-way bank alias (free)
  __shared__ ushort_t Bs[128][40];
  const int m0 = blockIdx.x * 128, n0 = blockIdx.y * 128;
  int tid = threadIdx.x;
  int wave = tid >> 6, lane = tid & 63;
  int wm = (wave & 1) * 64, wn = (wave >> 1) * 64;
  int quad = lane >> 4, l16 = lane & 15;
  f32x4 acc[4][4];
  #pragma unroll
  for (int i = 0; i < 4; ++i)
    #pragma unroll
    for (int j = 0; j < 4; ++j) acc[i][j] = (f32x4){0.f, 0.f, 0.f, 0.f};

  for (int k0 = 0; k0 < K; k0 += 32) {
    #pragma unroll
    for (int i = 0; i < 2; ++i) {
      int r = (tid >> 2) + i * 64;
      int kc = (tid & 3) * 8;
      uint4 va = *(const uint4*)(A + (size_t)(m0 + r) * lda + k0 + kc);
      *(uint4*)&As[r][kc] = va;
      uint4 vb = *(const uint4*)(Bt + (size_t)(n0 + r) * K + k0 + kc);
      *(uint4*)&Bs[r][kc] = vb;
    }
    __syncthreads();
    bf16x8 af[4], bfr[4];
    #pragma unroll
    for (int i = 0; i < 4; ++i) af[i] = *(const bf16x8*)&As[wm + i * 16 + l16][quad * 8];
    #pragma unroll
    for (int j = 0; j < 4; ++j) bfr[j] = *(const bf16x8*)&Bs[wn + j * 16 + l16][quad * 8];
    #pragma unroll
    for (int i = 0; i < 4; ++i)
      #pragma unroll
      for (int j = 0; j < 4; ++j)
        acc[i][j] = __builtin_amdgcn_mfma_f32_16x16x32_bf16(af[i], bfr[j], acc[i][j], 0, 0, 0);
    __syncthreads();
  }

  if (MODE == 0) {
    #pragma unroll
    for (int i = 0; i < 4; ++i)
      #pragma unroll
      for (int j = 0; j < 4; ++j) {
        int n = n0 + wn + j * 16 + l16;
        float bb = bias[n];
        #pragma unroll
        for (int reg = 0; reg < 4; ++reg) {
          int m = m0 + wm + i * 16 + quad * 4 + reg;
          C[(size_t)m * 512 + n] = acc[i][j][reg] + bb;
        }
      }
  } else {
    // wave's 64 cols = one dim-group: [r | z | i_n | h_n] x 16 dims
    int dim = ((n0 + wn) >> 6) * 16 + l16;
    float br = bias[n0 + wn + l16];
    float bz = bias[n0 + wn + 16 + l16];
    float bi = bias[n0 + wn + 32 + l16];
    float bh = bias[n0 + wn + 48 + l16];
    #pragma unroll
    for (int i = 0; i < 4; ++i)
      #pragma unroll
      for (int reg = 0; reg < 4; ++reg) {
        int m = m0 + wm + i * 16 + quad * 4 + reg;
        float pr  = acc[i][0][reg] + br;
        float pz  = acc[i][1][reg] + bz;
        float in_ = acc[i][2][reg] + bi;
        float hn  = acc[i][3][reg] + bh;
        float r = 1.0f / (1.0f + expf(-pr));
        float z = 1.0f / (1.0f + expf(-pz));
        float nn = tanhf(in_ + r * hn);
        size_t hi = (size_t)m * 128 + dim;
        float hv = (1.0f - z) * nn + z * h[hi];
        h[hi] = hv;
      }
  }
}

// Segment mean via sorted graph_ids, one block per graph, no atomics.
__global__ __launch_bounds__(128) void pool_kernel(const float* __restrict__ h,
    const int* __restrict__ gids, float* __restrict__ pooled) {
  __shared__ int lo_s, hi_s;
  int g = blockIdx.x, d = threadIdx.x;
  if (d == 0) {
    int lo = 0, hi = N_NODES;
    while (lo < hi) { int mid = (lo + hi) >> 1; if (gids[mid] < g) lo = mid + 1; else hi = mid; }
    lo_s = lo;
    int lo2 = lo, hi2 = N_NODES;
    while (lo2 < hi2) { int mid = (lo2 + hi2) >> 1; if (gids[mid] < g + 1) lo2 = mid + 1; else hi2 = mid; }
    hi_s = lo2;
  }
  __syncthreads();
  float s = 0.f;
  for (int n = lo_s; n < hi_s; ++n) s += h[(size_t)n * 128 + d];
  float cnt = (float)(hi_s - lo_s);
  pooled[g * 128 + d] = s / fmaxf(cnt, 1.f);
}

__global__ __launch_bounds__(256) void classifier_kernel(
    const float* __restrict__ pooled,
    const float* __restrict__ W1, const float* __restrict__ b1,
    const float* __restrict__ W2, const float* __restrict__ b2,
    float* __restrict__ out) {
  __shared__ float p[D];
  __shared__ float hid[256];
  __shared__ float wsum[4];
  int g = blockIdx.x;
  int t = threadIdx.x;
  if (t < D) p[t] = pooled[g * D + t];
  __syncthreads();
  float acc = b1[t];
  const float* w = W1 + (size_t)t * D;
  for (int k = 0; k < D; ++k) acc += p[k] * w[k];
  hid[t] = fmaxf(acc, 0.0f);
  __syncthreads();
  float v = hid[t] * W2[t];
  for (int off = 32; off > 0; off >>= 1) v += __shfl_down(v, off, 64);
  if ((t & 63) == 0) wsum[t >> 6] = v;
  __syncthreads();
  if (t == 0) {
    float s = wsum[0] + wsum[1] + wsum[2] + wsum[3] + b2[0];
    out[g] = 1.0f / (1.0f + expf(-s));
  }
}

extern "C" void kernel_launch(void* const* d_in, const int* in_sizes, int n_in,
                              void* d_out, int out_size, void* d_ws, size_t ws_size,
                              hipStream_t stream) {
  const float* features = (const float*)d_in[0];
  const int* esrc  = (const int*)d_in[1];
  const int* edst  = (const int*)d_in[2];
  const int* etype = (const int*)d_in[3];
  const int* gids  = (const int*)d_in[4];
  const float* W_msg = (const float*)d_in[5];
  const float* b_msg = (const float*)d_in[6];
  const float* W_ih  = (const float*)d_in[7];
  const float* W_hh  = (const float*)d_in[8];
  const float* b_ih  = (const float*)d_in[9];
  const float* b_hh  = (const float*)d_in[10];
  const float* W1 = (const float*)d_in[11];
  const float* b1 = (const float*)d_in[12];
  const float* W2 = (const float*)d_in[13];
  const float* b2 = (const float*)d_in[14];
  float* out = (float*)d_out;

  char* ws = (char*)d_ws;
  size_t off_b = 0;
  auto alloc = [&](size_t bytes) -> void* {
    void* p = ws + off_b;
    off_b += (bytes + 255) & ~(size_t)255;
    return p;
  };
  float*    h      = (float*)alloc((size_t)M_PAD * 128 * 4);      // 25.6 MB
  ushort_t* ah     = (ushort_t*)alloc((size_t)M_PAD * 256 * 2);   // 25.6 MB  [a | h] bf16
  float*    T      = (float*)alloc((size_t)M_PAD * 512 * 4);      // 102.5 MB
  ushort_t* WmsgT  = (ushort_t*)alloc(512 * 128 * 2);
  ushort_t* WgT    = (ushort_t*)alloc(512 * 256 * 2);
  float*    gbias  = (float*)alloc(512 * 4);
  int*      cnt    = (int*)alloc((size_t)N_NODES * 4);
  int*      offs   = (int*)alloc((size_t)(N_NODES + 1) * 4);
  int*      cursor = (int*)alloc((size_t)N_NODES * 4);
  int*      payload= (int*)alloc((size_t)N_EDGES * 4);
  float*    pooled = (float*)alloc(N_GRAPHS * 128 * 4);

  // ---- prologue ----
  pad_kernel<<<(N_NODES * 128 + 255) / 256, 256, 0, stream>>>(features, h);
  cast_h_kernel<<<(N_NODES * 128 + 255) / 256, 256, 0, stream>>>(h, ah);
  prep_wmsg<<<(512 * 128 + 255) / 256, 256, 0, stream>>>(W_msg, WmsgT);
  prep_wg<<<(512 * 256 + 255) / 256, 256, 0, stream>>>(W_ih, W_hh, b_ih, b_hh, WgT, gbias);
  hipMemsetAsync(cnt, 0, (size_t)N_NODES * 4, stream);
  hipMemsetAsync(cursor, 0, (size_t)N_NODES * 4, stream);
  hist_kernel<<<(N_EDGES + 255) / 256, 256, 0, stream>>>(edst, cnt);
  scan_kernel<<<1, 1024, 0, stream>>>(cnt, offs);
  fill_kernel<<<(N_EDGES + 255) / 256, 256, 0, stream>>>(esrc, edst, etype, offs, cursor, payload);

  dim3 ggrid(M_PAD / 128, 4);
  for (int step = 0; step < N_STEPS; ++step) {
    // T[n][t*128+f] = h @ W_msg[t] + b_msg[t]
    mfma_gemm<0><<<ggrid, 256, 0, stream>>>(ah + 128, 256, 128, WmsgT, T, b_msg, nullptr);
    // a-part of ah = bf16(scatter-sum)
    gather_kernel<<<N_NODES, 128, 0, stream>>>(offs, payload, T, ah);
    // fused GRU GEMM + gate epilogue, h updated in place
    mfma_gemm<1><<<ggrid, 256, 0, stream>>>(ah, 256, 256, WgT, nullptr, gbias, h);
    // refresh bf16 h copy for next step's GEMMs
    cast_h_kernel<<<(N_NODES * 128 + 255) / 256, 256, 0, stream>>>(h, ah);
  }

  pool_kernel<<<N_GRAPHS, 128, 0, stream>>>(h, gids, pooled);
  classifier_kernel<<<N_GRAPHS, 256, 0, stream>>>(pooled, W1, b1, W2, b2, out);
}

// Round 3
// 1455.380 us; speedup vs baseline: 4.3973x; 1.2274x over previous
//
#include <hip/hip_runtime.h>
#include <hip/hip_bf16.h>
#include <math.h>

#define N_NODES 50000
#define M_PAD   50048   // 391 * 128
#define N_EDGES 800000
#define N_GRAPHS 100
#define IN_DIM 100
#define D 128
#define N_STEPS 8

typedef unsigned short ushort_t;
typedef __bf16 bf16x8 __attribute__((ext_vector_type(8)));
typedef float f32x4 __attribute__((ext_vector_type(4)));

__device__ inline ushort_t f2b(float f) {
  __hip_bfloat16 b = __float2bfloat16(f);
  return *reinterpret_cast<ushort_t*>(&b);
}
__device__ inline float b2f(ushort_t u) {
  unsigned int x = ((unsigned int)u) << 16;
  return __builtin_bit_cast(float, x);
}

// h[n][d] = d < IN_DIM ? features[n][d] : 0   (fp32 master state)
__global__ void pad_kernel(const float* __restrict__ feat, float* __restrict__ h) {
  int idx = blockIdx.x * blockDim.x + threadIdx.x;
  if (idx >= N_NODES * D) return;
  int n = idx >> 7, d = idx & 127;
  h[idx] = (d < IN_DIM) ? feat[n * IN_DIM + d] : 0.0f;
}

// ah[n][128+d] = bf16(h[n][d])  (prologue only)
__global__ void cast_h_kernel(const float* __restrict__ h, ushort_t* __restrict__ ah) {
  int idx = blockIdx.x * blockDim.x + threadIdx.x;
  if (idx >= N_NODES * D) return;
  int n = idx >> 7, d = idx & 127;
  ah[(size_t)n * 256 + 128 + d] = f2b(h[idx]);
}

// WmsgT[col][k] = bf16(W_msg[t][k][f]), col = t*128+f  (n-major, k-contiguous)
__global__ void prep_wmsg(const float* __restrict__ W_msg, ushort_t* __restrict__ WmsgT) {
  int idx = blockIdx.x * blockDim.x + threadIdx.x;
  if (idx >= 512 * 128) return;
  int col = idx >> 7, k = idx & 127;
  int t = col >> 7, f = col & 127;
  WmsgT[col * 128 + k] = f2b(W_msg[((size_t)t * 128 + k) * 128 + f]);
}

// Permuted fused GRU weight, n-major k-contiguous bf16.
// col' = g*64 + gate*16 + r ; dim d = g*16 + r ; K: k<128 = a (W_ih), k>=128 = h (W_hh)
__global__ void prep_wg(const float* __restrict__ W_ih, const float* __restrict__ W_hh,
                        const float* __restrict__ b_ih, const float* __restrict__ b_hh,
                        ushort_t* __restrict__ WgT, float* __restrict__ gbias) {
  int idx = blockIdx.x * blockDim.x + threadIdx.x;
  if (idx >= 512 * 256) return;
  int colp = idx >> 8, k = idx & 255;
  int g = colp >> 6, gate = (colp >> 4) & 3, r = colp & 15;
  int d = g * 16 + r;
  float v;
  if (gate == 3)      v = (k < 128) ? 0.f : W_hh[(size_t)(256 + d) * 128 + (k - 128)];
  else if (gate == 2) v = (k < 128) ? W_ih[(size_t)(256 + d) * 128 + k] : 0.f;
  else {
    int j0 = (gate == 0) ? d : 128 + d;
    v = (k < 128) ? W_ih[(size_t)j0 * 128 + k] : W_hh[(size_t)j0 * 128 + (k - 128)];
  }
  WgT[(size_t)colp * 256 + k] = f2b(v);
  if (k == 0) {
    float bb = (gate == 0) ? b_ih[d] + b_hh[d]
             : (gate == 1) ? b_ih[128 + d] + b_hh[128 + d]
             : (gate == 2) ? b_ih[256 + d] : b_hh[256 + d];
    gbias[colp] = bb;
  }
}

// ---- CSR build ----
__global__ void hist_kernel(const int* __restrict__ edst, int* __restrict__ cnt) {
  int e = blockIdx.x * 256 + threadIdx.x;
  if (e >= N_EDGES) return;
  atomicAdd(&cnt[edst[e]], 1);
}

// single-block hierarchical scan: wave shfl-scan -> wave-sum scan -> carry
__global__ __launch_bounds__(1024) void scan_kernel(const int* __restrict__ cnt,
                                                    int* __restrict__ off) {
  __shared__ int wsum[16];
  __shared__ int carry_s;
  int t = threadIdx.x;
  int lane = t & 63, wid = t >> 6;
  if (t == 0) { carry_s = 0; off[0] = 0; }
  __syncthreads();
  for (int base = 0; base < N_NODES; base += 1024) {
    int i = base + t;
    int x = (i < N_NODES) ? cnt[i] : 0;
    #pragma unroll
    for (int s = 1; s < 64; s <<= 1) {
      int y = __shfl_up(x, s, 64);
      if (lane >= s) x += y;
    }
    if (lane == 63) wsum[wid] = x;
    __syncthreads();
    if (wid == 0) {
      int w = (lane < 16) ? wsum[lane] : 0;
      #pragma unroll
      for (int s = 1; s < 16; s <<= 1) {
        int y = __shfl_up(w, s, 64);
        if (lane >= s) w += y;
      }
      if (lane < 16) wsum[lane] = w;
    }
    __syncthreads();
    int wb = (wid > 0) ? wsum[wid - 1] : 0;
    int total = wsum[15];
    int carry = carry_s;
    if (i < N_NODES) off[i + 1] = carry + wb + x;
    __syncthreads();
    if (t == 0) carry_s = carry + total;
    __syncthreads();
  }
}

__global__ void fill_kernel(const int* __restrict__ esrc, const int* __restrict__ edst,
                            const int* __restrict__ etype, const int* __restrict__ off,
                            int* __restrict__ cursor, int* __restrict__ payload) {
  int e = blockIdx.x * 256 + threadIdx.x;
  if (e >= N_EDGES) return;
  int dd = edst[e];
  int pos = atomicAdd(&cursor[dd], 1);
  payload[off[dd] + pos] = (esrc[e] << 2) | etype[e];
}

// one wave per node, 2 dims per lane; read bf16 T rows, write packed bf16 a.
__global__ __launch_bounds__(256) void gather_kernel(const int* __restrict__ off,
    const int* __restrict__ payload, const ushort_t* __restrict__ T,
    ushort_t* __restrict__ ah) {
  int n = blockIdx.x * 4 + (threadIdx.x >> 6);
  int lane = threadIdx.x & 63;
  if (n >= N_NODES) return;
  int s = off[n], e = off[n + 1];
  float acc0 = 0.f, acc1 = 0.f;
  for (int i = s; i < e; ++i) {
    int p = payload[i];
    const unsigned int* row =
        (const unsigned int*)(T + (size_t)(p >> 2) * 512 + (p & 3) * 128);
    unsigned int u = row[lane];
    acc0 += b2f((ushort_t)(u & 0xffff));
    acc1 += b2f((ushort_t)(u >> 16));
  }
  unsigned int packed = (unsigned int)f2b(acc0) | ((unsigned int)f2b(acc1) << 16);
  *(unsigned int*)(ah + (size_t)n * 256 + lane * 2) = packed;
}

// ---- bf16 MFMA GEMM, 128x128 tile, 4 waves, 16x16x32 ----
// MODE 0: Tout[m][n] = bf16(acc + bias[n])  (ldc=512)
// MODE 1: GRU epilogue (permuted gate cols); h fp32 in place; bf16 h -> ah_next.
template <int MODE>
__global__ __launch_bounds__(256) void mfma_gemm(
    const ushort_t* __restrict__ A, int lda, int K,
    const ushort_t* __restrict__ Bt,
    ushort_t* __restrict__ Tout, const float* __restrict__ bias,
    float* __restrict__ h, ushort_t* __restrict__ ah_next) {
  __shared__ ushort_t As[128][40];   // 80B stride: 2-way bank alias (free)
  __shared__ ushort_t Bs[128][40];
  const int m0 = blockIdx.x * 128, n0 = blockIdx.y * 128;
  int tid = threadIdx.x;
  int wave = tid >> 6, lane = tid & 63;
  int wm = (wave & 1) * 64, wn = (wave >> 1) * 64;
  int quad = lane >> 4, l16 = lane & 15;
  f32x4 acc[4][4];
  #pragma unroll
  for (int i = 0; i < 4; ++i)
    #pragma unroll
    for (int j = 0; j < 4; ++j) acc[i][j] = (f32x4){0.f, 0.f, 0.f, 0.f};

  for (int k0 = 0; k0 < K; k0 += 32) {
    #pragma unroll
    for (int i = 0; i < 2; ++i) {
      int r = (tid >> 2) + i * 64;
      int kc = (tid & 3) * 8;
      uint4 va = *(const uint4*)(A + (size_t)(m0 + r) * lda + k0 + kc);
      *(uint4*)&As[r][kc] = va;
      uint4 vb = *(const uint4*)(Bt + (size_t)(n0 + r) * K + k0 + kc);
      *(uint4*)&Bs[r][kc] = vb;
    }
    __syncthreads();
    bf16x8 af[4], bfr[4];
    #pragma unroll
    for (int i = 0; i < 4; ++i) af[i] = *(const bf16x8*)&As[wm + i * 16 + l16][quad * 8];
    #pragma unroll
    for (int j = 0; j < 4; ++j) bfr[j] = *(const bf16x8*)&Bs[wn + j * 16 + l16][quad * 8];
    #pragma unroll
    for (int i = 0; i < 4; ++i)
      #pragma unroll
      for (int j = 0; j < 4; ++j)
        acc[i][j] = __builtin_amdgcn_mfma_f32_16x16x32_bf16(af[i], bfr[j], acc[i][j], 0, 0, 0);
    __syncthreads();
  }

  if (MODE == 0) {
    #pragma unroll
    for (int i = 0; i < 4; ++i)
      #pragma unroll
      for (int j = 0; j < 4; ++j) {
        int n = n0 + wn + j * 16 + l16;
        float bb = bias[n];
        #pragma unroll
        for (int reg = 0; reg < 4; ++reg) {
          int m = m0 + wm + i * 16 + quad * 4 + reg;
          Tout[(size_t)m * 512 + n] = f2b(acc[i][j][reg] + bb);
        }
      }
  } else {
    int dim = ((n0 + wn) >> 6) * 16 + l16;
    float br = bias[n0 + wn + l16];
    float bz = bias[n0 + wn + 16 + l16];
    float bi = bias[n0 + wn + 32 + l16];
    float bh = bias[n0 + wn + 48 + l16];
    #pragma unroll
    for (int i = 0; i < 4; ++i)
      #pragma unroll
      for (int reg = 0; reg < 4; ++reg) {
        int m = m0 + wm + i * 16 + quad * 4 + reg;
        float pr  = acc[i][0][reg] + br;
        float pz  = acc[i][1][reg] + bz;
        float in_ = acc[i][2][reg] + bi;
        float hn  = acc[i][3][reg] + bh;
        float r = 1.0f / (1.0f + expf(-pr));
        float z = 1.0f / (1.0f + expf(-pz));
        float nn = tanhf(in_ + r * hn);
        size_t hi = (size_t)m * 128 + dim;
        float hv = (1.0f - z) * nn + z * h[hi];
        h[hi] = hv;
        ah_next[(size_t)m * 256 + 128 + dim] = f2b(hv);
      }
  }
}

// partial pooling: grid (graph, chunk); 8-way atomic contention max.
__global__ __launch_bounds__(128) void pool_kernel(const float* __restrict__ h,
    const int* __restrict__ gids, float* __restrict__ pooled, float* __restrict__ gcnt) {
  __shared__ int lo_s, hi_s;
  int g = blockIdx.x, c = blockIdx.y, d = threadIdx.x;
  if (d == 0) {
    int lo = 0, hi = N_NODES;
    while (lo < hi) { int mid = (lo + hi) >> 1; if (gids[mid] < g) lo = mid + 1; else hi = mid; }
    lo_s = lo;
    int lo2 = lo, hi2 = N_NODES;
    while (lo2 < hi2) { int mid = (lo2 + hi2) >> 1; if (gids[mid] < g + 1) lo2 = mid + 1; else hi2 = mid; }
    hi_s = lo2;
  }
  __syncthreads();
  int lo = lo_s, hi = hi_s;
  int len = hi - lo;
  int b = lo + (int)(((long long)len * c) >> 3);
  int e = lo + (int)(((long long)len * (c + 1)) >> 3);
  float s = 0.f;
  for (int n = b; n < e; ++n) s += h[(size_t)n * 128 + d];
  if (e > b) atomicAdd(&pooled[g * 128 + d], s);
  if (c == 0 && d == 0) gcnt[g] = (float)len;
}

__global__ __launch_bounds__(256) void classifier_kernel(
    const float* __restrict__ pooled, const float* __restrict__ gcnt,
    const float* __restrict__ W1, const float* __restrict__ b1,
    const float* __restrict__ W2, const float* __restrict__ b2,
    float* __restrict__ out) {
  __shared__ float p[D];
  __shared__ float hid[256];
  __shared__ float wsum[4];
  int g = blockIdx.x;
  int t = threadIdx.x;
  float cnt = fmaxf(gcnt[g], 1.0f);
  if (t < D) p[t] = pooled[g * D + t] / cnt;
  __syncthreads();
  float acc = b1[t];
  const float* w = W1 + (size_t)t * D;
  for (int k = 0; k < D; ++k) acc += p[k] * w[k];
  hid[t] = fmaxf(acc, 0.0f);
  __syncthreads();
  float v = hid[t] * W2[t];
  for (int off = 32; off > 0; off >>= 1) v += __shfl_down(v, off, 64);
  if ((t & 63) == 0) wsum[t >> 6] = v;
  __syncthreads();
  if (t == 0) {
    float s = wsum[0] + wsum[1] + wsum[2] + wsum[3] + b2[0];
    out[g] = 1.0f / (1.0f + expf(-s));
  }
}

extern "C" void kernel_launch(void* const* d_in, const int* in_sizes, int n_in,
                              void* d_out, int out_size, void* d_ws, size_t ws_size,
                              hipStream_t stream) {
  const float* features = (const float*)d_in[0];
  const int* esrc  = (const int*)d_in[1];
  const int* edst  = (const int*)d_in[2];
  const int* etype = (const int*)d_in[3];
  const int* gids  = (const int*)d_in[4];
  const float* W_msg = (const float*)d_in[5];
  const float* b_msg = (const float*)d_in[6];
  const float* W_ih  = (const float*)d_in[7];
  const float* W_hh  = (const float*)d_in[8];
  const float* b_ih  = (const float*)d_in[9];
  const float* b_hh  = (const float*)d_in[10];
  const float* W1 = (const float*)d_in[11];
  const float* b1 = (const float*)d_in[12];
  const float* W2 = (const float*)d_in[13];
  const float* b2 = (const float*)d_in[14];
  float* out = (float*)d_out;

  char* ws = (char*)d_ws;
  size_t off_b = 0;
  auto alloc = [&](size_t bytes) -> void* {
    void* p = ws + off_b;
    off_b += (bytes + 255) & ~(size_t)255;
    return p;
  };
  float*    h      = (float*)alloc((size_t)M_PAD * 128 * 4);      // 25.6 MB fp32 master
  ushort_t* ahA    = (ushort_t*)alloc((size_t)M_PAD * 256 * 2);   // 25.6 MB [a|h] bf16
  ushort_t* ahB    = (ushort_t*)alloc((size_t)M_PAD * 256 * 2);   // ping-pong partner
  ushort_t* T      = (ushort_t*)alloc((size_t)M_PAD * 512 * 2);   // 51.2 MB bf16
  ushort_t* WmsgT  = (ushort_t*)alloc(512 * 128 * 2);
  ushort_t* WgT    = (ushort_t*)alloc(512 * 256 * 2);
  float*    gbias  = (float*)alloc(512 * 4);
  int*      cnt    = (int*)alloc((size_t)N_NODES * 4);
  int*      offs   = (int*)alloc((size_t)(N_NODES + 1) * 4);
  int*      cursor = (int*)alloc((size_t)N_NODES * 4);
  int*      payload= (int*)alloc((size_t)N_EDGES * 4);
  float*    pooled = (float*)alloc(N_GRAPHS * 128 * 4);
  float*    gcnt   = (float*)alloc(N_GRAPHS * 4);

  // ---- prologue ----
  pad_kernel<<<(N_NODES * 128 + 255) / 256, 256, 0, stream>>>(features, h);
  cast_h_kernel<<<(N_NODES * 128 + 255) / 256, 256, 0, stream>>>(h, ahA);
  prep_wmsg<<<(512 * 128 + 255) / 256, 256, 0, stream>>>(W_msg, WmsgT);
  prep_wg<<<(512 * 256 + 255) / 256, 256, 0, stream>>>(W_ih, W_hh, b_ih, b_hh, WgT, gbias);
  hipMemsetAsync(cnt, 0, (size_t)N_NODES * 4, stream);
  hipMemsetAsync(cursor, 0, (size_t)N_NODES * 4, stream);
  hist_kernel<<<(N_EDGES + 255) / 256, 256, 0, stream>>>(edst, cnt);
  scan_kernel<<<1, 1024, 0, stream>>>(cnt, offs);
  fill_kernel<<<(N_EDGES + 255) / 256, 256, 0, stream>>>(esrc, edst, etype, offs, cursor, payload);

  dim3 ggrid(M_PAD / 128, 4);
  ushort_t* cur = ahA;
  ushort_t* nxt = ahB;
  for (int step = 0; step < N_STEPS; ++step) {
    // T[n][t*128+f] = bf16(h @ W_msg[t] + b_msg[t])
    mfma_gemm<0><<<ggrid, 256, 0, stream>>>(cur + 128, 256, 128, WmsgT, T, b_msg, nullptr, nullptr);
    // a-part of cur = bf16(scatter-sum of T rows)
    gather_kernel<<<(N_NODES + 3) / 4, 256, 0, stream>>>(offs, payload, T, cur);
    // fused GRU GEMM + gate epilogue: fp32 h in place, bf16 h into nxt
    mfma_gemm<1><<<ggrid, 256, 0, stream>>>(cur, 256, 256, WgT, nullptr, gbias, h, nxt);
    ushort_t* tmp = cur; cur = nxt; nxt = tmp;
  }

  hipMemsetAsync(pooled, 0, (size_t)N_GRAPHS * 128 * 4, stream);
  pool_kernel<<<dim3(N_GRAPHS, 8), 128, 0, stream>>>(h, gids, pooled, gcnt);
  classifier_kernel<<<N_GRAPHS, 256, 0, stream>>>(pooled, gcnt, W1, b1, W2, b2, out);
}

// Round 4
// 1227.504 us; speedup vs baseline: 5.2136x; 1.1856x over previous
//
#include <hip/hip_runtime.h>
#include <hip/hip_bf16.h>
#include <math.h>

#define N_NODES 50000
#define M_PAD   50048   // 391 * 128
#define N_EDGES 800000
#define N_GRAPHS 100
#define IN_DIM 100
#define D 128
#define N_STEPS 8
#define NBINS (N_NODES * 4)      // (dst, type) bins
#define SCAN_BLOCKS 196          // 196*1024 = 200704 >= NBINS

typedef unsigned short ushort_t;
typedef __bf16 bf16x8 __attribute__((ext_vector_type(8)));
typedef float f32x4 __attribute__((ext_vector_type(4)));

__device__ inline ushort_t f2b(float f) {
  __hip_bfloat16 b = __float2bfloat16(f);
  return *reinterpret_cast<ushort_t*>(&b);
}
__device__ inline float b2f(unsigned int u16) {
  unsigned int x = u16 << 16;
  return __builtin_bit_cast(float, x);
}

// h[n][d] = d < IN_DIM ? features[n][d] : 0   (fp32 master state)
__global__ void pad_kernel(const float* __restrict__ feat, float* __restrict__ h) {
  int idx = blockIdx.x * blockDim.x + threadIdx.x;
  if (idx >= N_NODES * D) return;
  int n = idx >> 7, d = idx & 127;
  h[idx] = (d < IN_DIM) ? feat[n * IN_DIM + d] : 0.0f;
}

// ah[n][128+d] = bf16(h[n][d])  (prologue only)
__global__ void cast_h_kernel(const float* __restrict__ h, ushort_t* __restrict__ ah) {
  int idx = blockIdx.x * blockDim.x + threadIdx.x;
  if (idx >= N_NODES * D) return;
  int n = idx >> 7, d = idx & 127;
  ah[(size_t)n * 256 + 128 + d] = f2b(h[idx]);
}

// BtS[f][t*128+k] = bf16(W_msg[t][k][f])   (n-major, k-contiguous, K=512)
__global__ void prep_bts(const float* __restrict__ W_msg, ushort_t* __restrict__ BtS) {
  int idx = blockIdx.x * blockDim.x + threadIdx.x;
  if (idx >= 128 * 512) return;
  int f = idx >> 9, kp = idx & 511;
  int t = kp >> 7, k = kp & 127;
  BtS[(size_t)f * 512 + kp] = f2b(W_msg[((size_t)t * 128 + k) * 128 + f]);
}

// Permuted fused GRU weight, n-major k-contiguous bf16.
// col' = g*64 + gate*16 + r ; dim d = g*16 + r ; K: k<128 = a (W_ih), k>=128 = h (W_hh)
__global__ void prep_wg(const float* __restrict__ W_ih, const float* __restrict__ W_hh,
                        const float* __restrict__ b_ih, const float* __restrict__ b_hh,
                        ushort_t* __restrict__ WgT, float* __restrict__ gbias) {
  int idx = blockIdx.x * blockDim.x + threadIdx.x;
  if (idx >= 512 * 256) return;
  int colp = idx >> 8, k = idx & 255;
  int g = colp >> 6, gate = (colp >> 4) & 3, r = colp & 15;
  int d = g * 16 + r;
  float v;
  if (gate == 3)      v = (k < 128) ? 0.f : W_hh[(size_t)(256 + d) * 128 + (k - 128)];
  else if (gate == 2) v = (k < 128) ? W_ih[(size_t)(256 + d) * 128 + k] : 0.f;
  else {
    int j0 = (gate == 0) ? d : 128 + d;
    v = (k < 128) ? W_ih[(size_t)j0 * 128 + k] : W_hh[(size_t)j0 * 128 + (k - 128)];
  }
  WgT[(size_t)colp * 256 + k] = f2b(v);
  if (k == 0) {
    float bb = (gate == 0) ? b_ih[d] + b_hh[d]
             : (gate == 1) ? b_ih[128 + d] + b_hh[128 + d]
             : (gate == 2) ? b_ih[256 + d] : b_hh[256 + d];
    gbias[colp] = bb;
  }
}

// ---- type-segmented CSR build over NBINS = dst*4+type ----
__global__ void hist_kernel(const int* __restrict__ edst, const int* __restrict__ etype,
                            int* __restrict__ cnt2) {
  int e = blockIdx.x * 256 + threadIdx.x;
  if (e >= N_EDGES) return;
  atomicAdd(&cnt2[edst[e] * 4 + etype[e]], 1);
}

// 3-phase scan: A) per-block inclusive scan + block sums
__global__ __launch_bounds__(1024) void scanA(const int* __restrict__ cnt2,
                                              int* __restrict__ tmp, int* __restrict__ bsum) {
  __shared__ int wsum[16];
  int b = blockIdx.x, t = threadIdx.x;
  int i = b * 1024 + t;
  int lane = t & 63, wid = t >> 6;
  int x = (i < NBINS) ? cnt2[i] : 0;
  #pragma unroll
  for (int s = 1; s < 64; s <<= 1) {
    int y = __shfl_up(x, s, 64);
    if (lane >= s) x += y;
  }
  if (lane == 63) wsum[wid] = x;
  __syncthreads();
  if (wid == 0) {
    int w = (lane < 16) ? wsum[lane] : 0;
    #pragma unroll
    for (int s = 1; s < 16; s <<= 1) {
      int y = __shfl_up(w, s, 64);
      if (lane >= s) w += y;
    }
    if (lane < 16) wsum[lane] = w;
  }
  __syncthreads();
  int wb = (wid > 0) ? wsum[wid - 1] : 0;
  tmp[i] = wb + x;
  if (t == 1023) bsum[b] = wsum[15];
}

// B) one wave scans the SCAN_BLOCKS block sums -> exclusive prefixes
__global__ __launch_bounds__(64) void scanB(const int* __restrict__ bsum,
                                            int* __restrict__ bpre) {
  int lane = threadIdx.x;
  int carry = 0;
  for (int base = 0; base < SCAN_BLOCKS; base += 64) {
    int idx = base + lane;
    int v = (idx < SCAN_BLOCKS) ? bsum[idx] : 0;
    int x = v;
    #pragma unroll
    for (int s = 1; s < 64; s <<= 1) {
      int y = __shfl_up(x, s, 64);
      if (lane >= s) x += y;
    }
    if (idx < SCAN_BLOCKS) bpre[idx] = carry + x - v;
    carry += __shfl(x, 63, 64);
  }
}

// C) offs2[i+1] = tmp[i] + bpre[block]
__global__ __launch_bounds__(1024) void scanC(const int* __restrict__ tmp,
                                              const int* __restrict__ bpre,
                                              int* __restrict__ offs2) {
  int b = blockIdx.x, t = threadIdx.x;
  int i = b * 1024 + t;
  if (i < NBINS) offs2[i + 1] = tmp[i] + bpre[b];
  if (i == 0) offs2[0] = 0;
}

__global__ void fill_kernel(const int* __restrict__ esrc, const int* __restrict__ edst,
                            const int* __restrict__ etype, const int* __restrict__ offs2,
                            int* __restrict__ cursor, int* __restrict__ payload) {
  int e = blockIdx.x * 256 + threadIdx.x;
  if (e >= N_EDGES) return;
  int key = edst[e] * 4 + etype[e];
  int pos = atomicAdd(&cursor[key], 1);
  payload[offs2[key] + pos] = esrc[e];
}

// One wave per node: S[n][t][:] = sum of bf16 h[src] over type-t in-edges; cnt per type.
// Random reads hit the 12.8 MB bf16 h footprint (hot in L2/L3).
__global__ __launch_bounds__(256) void gather_kernel(const int* __restrict__ offs2,
    const int* __restrict__ payload, const ushort_t* __restrict__ hb,
    ushort_t* __restrict__ S, float* __restrict__ cntf) {
  int n = blockIdx.x * 4 + (threadIdx.x >> 6);
  int lane = threadIdx.x & 63;
  if (n >= N_NODES) return;
  #pragma unroll
  for (int t = 0; t < 4; ++t) {
    int s = offs2[n * 4 + t], e = offs2[n * 4 + t + 1];
    float a0 = 0.f, a1 = 0.f;
    int i = s;
    for (; i + 1 < e; i += 2) {
      int s0 = payload[i], s1 = payload[i + 1];
      unsigned int u0 = *(const unsigned int*)(hb + (size_t)s0 * 256 + 128 + lane * 2);
      unsigned int u1 = *(const unsigned int*)(hb + (size_t)s1 * 256 + 128 + lane * 2);
      a0 += b2f(u0 & 0xffff) + b2f(u1 & 0xffff);
      a1 += b2f(u0 >> 16) + b2f(u1 >> 16);
    }
    if (i < e) {
      int s0 = payload[i];
      unsigned int u0 = *(const unsigned int*)(hb + (size_t)s0 * 256 + 128 + lane * 2);
      a0 += b2f(u0 & 0xffff);
      a1 += b2f(u0 >> 16);
    }
    unsigned int packed = (unsigned int)f2b(a0) | ((unsigned int)f2b(a1) << 16);
    *(unsigned int*)(S + (size_t)n * 512 + t * 128 + lane * 2) = packed;
    if (lane == 0) cntf[n * 4 + t] = (float)(e - s);
  }
}

// ---- bf16 MFMA GEMM, 128x128 tile, 4 waves, 16x16x32 ----
// MODE 2: a-GEMM (K=512, N=128): val = acc + sum_t cnt[m][t]*b_msg[t][n]; bf16 -> ah a-part.
// MODE 1: GRU epilogue (permuted gate cols); h fp32 in place; bf16 h -> ah_next h-part.
template <int MODE>
__global__ __launch_bounds__(256) void mfma_gemm(
    const ushort_t* __restrict__ A, int lda, int K,
    const ushort_t* __restrict__ Bt,
    const float* __restrict__ bias, const float* __restrict__ b_msg,
    const float* __restrict__ cntf,
    ushort_t* __restrict__ ah_out, float* __restrict__ h) {
  __shared__ ushort_t As[128][40];   // 80B stride: 2-way bank alias (free)
  __shared__ ushort_t Bs[128][40];
  const int m0 = blockIdx.x * 128, n0 = blockIdx.y * 128;
  int tid = threadIdx.x;
  int wave = tid >> 6, lane = tid & 63;
  int wm = (wave & 1) * 64, wn = (wave >> 1) * 64;
  int quad = lane >> 4, l16 = lane & 15;
  f32x4 acc[4][4];
  #pragma unroll
  for (int i = 0; i < 4; ++i)
    #pragma unroll
    for (int j = 0; j < 4; ++j) acc[i][j] = (f32x4){0.f, 0.f, 0.f, 0.f};

  for (int k0 = 0; k0 < K; k0 += 32) {
    #pragma unroll
    for (int i = 0; i < 2; ++i) {
      int r = (tid >> 2) + i * 64;
      int kc = (tid & 3) * 8;
      uint4 va = *(const uint4*)(A + (size_t)(m0 + r) * lda + k0 + kc);
      *(uint4*)&As[r][kc] = va;
      uint4 vb = *(const uint4*)(Bt + (size_t)(n0 + r) * K + k0 + kc);
      *(uint4*)&Bs[r][kc] = vb;
    }
    __syncthreads();
    bf16x8 af[4], bfr[4];
    #pragma unroll
    for (int i = 0; i < 4; ++i) af[i] = *(const bf16x8*)&As[wm + i * 16 + l16][quad * 8];
    #pragma unroll
    for (int j = 0; j < 4; ++j) bfr[j] = *(const bf16x8*)&Bs[wn + j * 16 + l16][quad * 8];
    #pragma unroll
    for (int i = 0; i < 4; ++i)
      #pragma unroll
      for (int j = 0; j < 4; ++j)
        acc[i][j] = __builtin_amdgcn_mfma_f32_16x16x32_bf16(af[i], bfr[j], acc[i][j], 0, 0, 0);
    __syncthreads();
  }

  if (MODE == 2) {
    // n0 == 0 (N=128). Per-node bias: sum_t cnt[m][t] * b_msg[t][n].
    float bm[4][4];  // [j][t]
    #pragma unroll
    for (int j = 0; j < 4; ++j)
      #pragma unroll
      for (int t = 0; t < 4; ++t)
        bm[j][t] = b_msg[t * 128 + wn + j * 16 + l16];
    #pragma unroll
    for (int i = 0; i < 4; ++i)
      #pragma unroll
      for (int reg = 0; reg < 4; ++reg) {
        int m = m0 + wm + i * 16 + quad * 4 + reg;
        float4 c = *(const float4*)(cntf + (size_t)m * 4);
        #pragma unroll
        for (int j = 0; j < 4; ++j) {
          int n = wn + j * 16 + l16;
          float val = acc[i][j][reg] + c.x * bm[j][0] + c.y * bm[j][1]
                                     + c.z * bm[j][2] + c.w * bm[j][3];
          ah_out[(size_t)m * 256 + n] = f2b(val);
        }
      }
  } else {
    int dim = ((n0 + wn) >> 6) * 16 + l16;
    float br = bias[n0 + wn + l16];
    float bz = bias[n0 + wn + 16 + l16];
    float bi = bias[n0 + wn + 32 + l16];
    float bh = bias[n0 + wn + 48 + l16];
    #pragma unroll
    for (int i = 0; i < 4; ++i)
      #pragma unroll
      for (int reg = 0; reg < 4; ++reg) {
        int m = m0 + wm + i * 16 + quad * 4 + reg;
        float pr  = acc[i][0][reg] + br;
        float pz  = acc[i][1][reg] + bz;
        float in_ = acc[i][2][reg] + bi;
        float hn  = acc[i][3][reg] + bh;
        float r = 1.0f / (1.0f + expf(-pr));
        float z = 1.0f / (1.0f + expf(-pz));
        float nn = tanhf(in_ + r * hn);
        size_t hi = (size_t)m * 128 + dim;
        float hv = (1.0f - z) * nn + z * h[hi];
        h[hi] = hv;
        ah_out[(size_t)m * 256 + 128 + dim] = f2b(hv);
      }
  }
}

// partial pooling: grid (graph, chunk); 8-way atomic contention max.
__global__ __launch_bounds__(128) void pool_kernel(const float* __restrict__ h,
    const int* __restrict__ gids, float* __restrict__ pooled, float* __restrict__ gcnt) {
  __shared__ int lo_s, hi_s;
  int g = blockIdx.x, c = blockIdx.y, d = threadIdx.x;
  if (d == 0) {
    int lo = 0, hi = N_NODES;
    while (lo < hi) { int mid = (lo + hi) >> 1; if (gids[mid] < g) lo = mid + 1; else hi = mid; }
    lo_s = lo;
    int lo2 = lo, hi2 = N_NODES;
    while (lo2 < hi2) { int mid = (lo2 + hi2) >> 1; if (gids[mid] < g + 1) lo2 = mid + 1; else hi2 = mid; }
    hi_s = lo2;
  }
  __syncthreads();
  int lo = lo_s, hi = hi_s;
  int len = hi - lo;
  int b = lo + (int)(((long long)len * c) >> 3);
  int e = lo + (int)(((long long)len * (c + 1)) >> 3);
  float s = 0.f;
  for (int n = b; n < e; ++n) s += h[(size_t)n * 128 + d];
  if (e > b) atomicAdd(&pooled[g * 128 + d], s);
  if (c == 0 && d == 0) gcnt[g] = (float)len;
}

__global__ __launch_bounds__(256) void classifier_kernel(
    const float* __restrict__ pooled, const float* __restrict__ gcnt,
    const float* __restrict__ W1, const float* __restrict__ b1,
    const float* __restrict__ W2, const float* __restrict__ b2,
    float* __restrict__ out) {
  __shared__ float p[D];
  __shared__ float hid[256];
  __shared__ float wsum[4];
  int g = blockIdx.x;
  int t = threadIdx.x;
  float cnt = fmaxf(gcnt[g], 1.0f);
  if (t < D) p[t] = pooled[g * D + t] / cnt;
  __syncthreads();
  float acc = b1[t];
  const float* w = W1 + (size_t)t * D;
  for (int k = 0; k < D; ++k) acc += p[k] * w[k];
  hid[t] = fmaxf(acc, 0.0f);
  __syncthreads();
  float v = hid[t] * W2[t];
  for (int off = 32; off > 0; off >>= 1) v += __shfl_down(v, off, 64);
  if ((t & 63) == 0) wsum[t >> 6] = v;
  __syncthreads();
  if (t == 0) {
    float s = wsum[0] + wsum[1] + wsum[2] + wsum[3] + b2[0];
    out[g] = 1.0f / (1.0f + expf(-s));
  }
}

extern "C" void kernel_launch(void* const* d_in, const int* in_sizes, int n_in,
                              void* d_out, int out_size, void* d_ws, size_t ws_size,
                              hipStream_t stream) {
  const float* features = (const float*)d_in[0];
  const int* esrc  = (const int*)d_in[1];
  const int* edst  = (const int*)d_in[2];
  const int* etype = (const int*)d_in[3];
  const int* gids  = (const int*)d_in[4];
  const float* W_msg = (const float*)d_in[5];
  const float* b_msg = (const float*)d_in[6];
  const float* W_ih  = (const float*)d_in[7];
  const float* W_hh  = (const float*)d_in[8];
  const float* b_ih  = (const float*)d_in[9];
  const float* b_hh  = (const float*)d_in[10];
  const float* W1 = (const float*)d_in[11];
  const float* b1 = (const float*)d_in[12];
  const float* W2 = (const float*)d_in[13];
  const float* b2 = (const float*)d_in[14];
  float* out = (float*)d_out;

  char* ws = (char*)d_ws;
  size_t off_b = 0;
  auto alloc = [&](size_t bytes) -> void* {
    void* p = ws + off_b;
    off_b += (bytes + 255) & ~(size_t)255;
    return p;
  };
  float*    h      = (float*)alloc((size_t)M_PAD * 128 * 4);      // 25.6 MB fp32 master
  ushort_t* ahA    = (ushort_t*)alloc((size_t)M_PAD * 256 * 2);   // [a|h] bf16
  ushort_t* ahB    = (ushort_t*)alloc((size_t)M_PAD * 256 * 2);   // ping-pong partner
  ushort_t* S      = (ushort_t*)alloc((size_t)M_PAD * 512 * 2);   // 51.2 MB bf16
  float*    cntf   = (float*)alloc((size_t)M_PAD * 4 * 4);        // per-node type counts
  ushort_t* BtS    = (ushort_t*)alloc(128 * 512 * 2);
  ushort_t* WgT    = (ushort_t*)alloc(512 * 256 * 2);
  float*    gbias  = (float*)alloc(512 * 4);
  int*      cnt2   = (int*)alloc((size_t)NBINS * 4);
  int*      offs2  = (int*)alloc((size_t)(NBINS + 1) * 4);
  int*      cursor = (int*)alloc((size_t)NBINS * 4);
  int*      tmp    = (int*)alloc((size_t)SCAN_BLOCKS * 1024 * 4);
  int*      bsum   = (int*)alloc(SCAN_BLOCKS * 4);
  int*      bpre   = (int*)alloc(SCAN_BLOCKS * 4);
  int*      payload= (int*)alloc((size_t)N_EDGES * 4);
  float*    pooled = (float*)alloc(N_GRAPHS * 128 * 4);
  float*    gcnt   = (float*)alloc(N_GRAPHS * 4);

  // ---- prologue ----
  pad_kernel<<<(N_NODES * 128 + 255) / 256, 256, 0, stream>>>(features, h);
  cast_h_kernel<<<(N_NODES * 128 + 255) / 256, 256, 0, stream>>>(h, ahA);
  prep_bts<<<(128 * 512 + 255) / 256, 256, 0, stream>>>(W_msg, BtS);
  prep_wg<<<(512 * 256 + 255) / 256, 256, 0, stream>>>(W_ih, W_hh, b_ih, b_hh, WgT, gbias);
  hipMemsetAsync(cnt2, 0, (size_t)NBINS * 4, stream);
  hipMemsetAsync(cursor, 0, (size_t)NBINS * 4, stream);
  hist_kernel<<<(N_EDGES + 255) / 256, 256, 0, stream>>>(edst, etype, cnt2);
  scanA<<<SCAN_BLOCKS, 1024, 0, stream>>>(cnt2, tmp, bsum);
  scanB<<<1, 64, 0, stream>>>(bsum, bpre);
  scanC<<<SCAN_BLOCKS, 1024, 0, stream>>>(tmp, bpre, offs2);
  fill_kernel<<<(N_EDGES + 255) / 256, 256, 0, stream>>>(esrc, edst, etype, offs2, cursor, payload);

  ushort_t* cur = ahA;
  ushort_t* nxt = ahB;
  for (int step = 0; step < N_STEPS; ++step) {
    // S[n][t][:] = sum of h_src (bf16) over type-t in-edges
    gather_kernel<<<(N_NODES + 3) / 4, 256, 0, stream>>>(offs2, payload, cur, S, cntf);
    // a-part of cur = bf16(S @ [W_0;..;W_3] + cnt-weighted b_msg)
    mfma_gemm<2><<<dim3(M_PAD / 128, 1), 256, 0, stream>>>(
        S, 512, 512, BtS, nullptr, b_msg, cntf, cur, nullptr);
    // fused GRU GEMM + gate epilogue: fp32 h in place, bf16 h into nxt
    mfma_gemm<1><<<dim3(M_PAD / 128, 4), 256, 0, stream>>>(
        cur, 256, 256, WgT, gbias, nullptr, nullptr, nxt, h);
    ushort_t* t2 = cur; cur = nxt; nxt = t2;
  }

  hipMemsetAsync(pooled, 0, (size_t)N_GRAPHS * 128 * 4, stream);
  pool_kernel<<<dim3(N_GRAPHS, 8), 128, 0, stream>>>(h, gids, pooled, gcnt);
  classifier_kernel<<<N_GRAPHS, 256, 0, stream>>>(pooled, gcnt, W1, b1, W2, b2, out);
}